// Round 1
// baseline (118.377 us; speedup 1.0000x reference)
//
#include <hip/hip_runtime.h>

namespace {

constexpr int Bsz = 64;
constexpr int Nn  = 1024;
constexpr int Dd  = 512;
constexpr int NCH = 32;            // n-chunks for column reductions
constexpr int RPC = Nn / NCH;      // 32 rows per chunk
constexpr float SCALE = 0.044194173824159216f;  // 1/sqrt(512)

// Pass 1a: partial column sums of x over n-chunks. grid(B, NCH), block 128.
__global__ __launch_bounds__(128) void k_colsum(const float* __restrict__ x,
                                                float* __restrict__ part) {
  const int b = blockIdx.x, ch = blockIdx.y, t = threadIdx.x;
  const float* base = x + ((size_t)b * Nn + (size_t)ch * RPC) * Dd;
  float4 acc = make_float4(0.f, 0.f, 0.f, 0.f);
  for (int n = 0; n < RPC; ++n) {
    float4 v = *reinterpret_cast<const float4*>(base + (size_t)n * Dd + t * 4);
    acc.x += v.x; acc.y += v.y; acc.z += v.z; acc.w += v.w;
  }
  *reinterpret_cast<float4*>(part + (size_t)(b * NCH + ch) * Dd + t * 4) = acc;
}

// Pass 1b: xbar -> kbar = xbar@Wk^T + bk -> u = kbar@Wq, c = bq.kbar. grid(B), 512 thr.
__global__ __launch_bounds__(512) void k_prep(const float* __restrict__ part,
                                              const float* __restrict__ Wq,
                                              const float* __restrict__ bq,
                                              const float* __restrict__ Wk,
                                              const float* __restrict__ bk,
                                              float* __restrict__ u,
                                              float* __restrict__ c) {
  const int b = blockIdx.x, t = threadIdx.x;
  __shared__ __align__(16) float xbar[Dd];
  __shared__ float kbar[Dd];
  __shared__ float red[512];

  float acc = 0.f;
  for (int ch = 0; ch < NCH; ++ch) acc += part[(size_t)(b * NCH + ch) * Dd + t];
  xbar[t] = acc * (1.0f / Nn);
  __syncthreads();

  // kbar[e=t] = bk[t] + xbar . Wk_row[t]   (Wk is 1 MiB, L2-resident)
  const float4* w4  = reinterpret_cast<const float4*>(Wk + (size_t)t * Dd);
  const float4* xb4 = reinterpret_cast<const float4*>(xbar);
  float s = 0.f;
  for (int i = 0; i < Dd / 4; ++i) {
    float4 wv = w4[i]; float4 xv = xb4[i];
    s += wv.x * xv.x + wv.y * xv.y + wv.z * xv.z + wv.w * xv.w;
  }
  kbar[t] = bk[t] + s;
  __syncthreads();

  // u[d=t] = sum_e kbar[e] * Wq[e, t]  (coalesced column access)
  float uu = 0.f;
  for (int e = 0; e < Dd; ++e) uu += kbar[e] * Wq[(size_t)e * Dd + t];
  u[(size_t)b * Dd + t] = uu;

  red[t] = bq[t] * kbar[t];
  __syncthreads();
  for (int off = 256; off > 0; off >>= 1) {
    if (t < off) red[t] += red[t + off];
    __syncthreads();
  }
  if (t == 0) c[b] = red[0];
}

// Pass 2: s[b,n] = (x[b,n].u[b] + c[b]) * SCALE. grid(B, 16), block 256 (one wave/row).
__global__ __launch_bounds__(256) void k_scores(const float* __restrict__ x,
                                                const float* __restrict__ u,
                                                const float* __restrict__ c,
                                                float* __restrict__ s) {
  const int b = blockIdx.x, ch = blockIdx.y, t = threadIdx.x;
  __shared__ __align__(16) float us[Dd];
  us[t]       = u[(size_t)b * Dd + t];
  us[t + 256] = u[(size_t)b * Dd + t + 256];
  __syncthreads();
  const int wave = t >> 6, lane = t & 63;
  const float cb = c[b];
  const float4 u1 = *reinterpret_cast<const float4*>(us + lane * 4);
  const float4 u2 = *reinterpret_cast<const float4*>(us + 256 + lane * 4);
  constexpr int ROWS = 64;  // rows per block
  for (int r = wave; r < ROWS; r += 4) {
    const int n = ch * ROWS + r;
    const float4* xr = reinterpret_cast<const float4*>(x + ((size_t)b * Nn + n) * Dd);
    float4 a  = xr[lane];
    float4 bb = xr[64 + lane];
    float dot = a.x * u1.x + a.y * u1.y + a.z * u1.z + a.w * u1.w
              + bb.x * u2.x + bb.y * u2.y + bb.z * u2.z + bb.w * u2.w;
    for (int off = 32; off > 0; off >>= 1) dot += __shfl_xor(dot, off);
    if (lane == 0) s[(size_t)b * Nn + n] = (dot + cb) * SCALE;
  }
}

// Pass 3: softmax over n per batch. grid(B), block 256 (4 vals/thread).
__global__ __launch_bounds__(256) void k_softmax(const float* __restrict__ s,
                                                 float* __restrict__ w) {
  const int b = blockIdx.x, t = threadIdx.x;
  __shared__ float lmax[4], lsum[4];
  float v[4];
  for (int i = 0; i < 4; ++i) v[i] = s[(size_t)b * Nn + t + i * 256];
  float m = fmaxf(fmaxf(v[0], v[1]), fmaxf(v[2], v[3]));
  for (int off = 32; off > 0; off >>= 1) m = fmaxf(m, __shfl_xor(m, off));
  const int wave = t >> 6, lane = t & 63;
  if (lane == 0) lmax[wave] = m;
  __syncthreads();
  m = fmaxf(fmaxf(lmax[0], lmax[1]), fmaxf(lmax[2], lmax[3]));
  float e[4];
  float sum = 0.f;
  for (int i = 0; i < 4; ++i) { e[i] = expf(v[i] - m); sum += e[i]; }
  for (int off = 32; off > 0; off >>= 1) sum += __shfl_xor(sum, off);
  if (lane == 0) lsum[wave] = sum;
  __syncthreads();
  sum = lsum[0] + lsum[1] + lsum[2] + lsum[3];
  const float inv = 1.0f / sum;
  for (int i = 0; i < 4; ++i) w[(size_t)b * Nn + t + i * 256] = e[i] * inv;
}

// Pass 4a: partial weighted column sums. grid(B, NCH), block 128.
__global__ __launch_bounds__(128) void k_wsum(const float* __restrict__ x,
                                              const float* __restrict__ w,
                                              float* __restrict__ part) {
  const int b = blockIdx.x, ch = blockIdx.y, t = threadIdx.x;
  const float* base = x + ((size_t)b * Nn + (size_t)ch * RPC) * Dd;
  const float* wb = w + (size_t)b * Nn + (size_t)ch * RPC;
  float4 acc = make_float4(0.f, 0.f, 0.f, 0.f);
  for (int n = 0; n < RPC; ++n) {
    const float wn = wb[n];
    float4 v = *reinterpret_cast<const float4*>(base + (size_t)n * Dd + t * 4);
    acc.x += wn * v.x; acc.y += wn * v.y; acc.z += wn * v.z; acc.w += wn * v.w;
  }
  *reinterpret_cast<float4*>(part + (size_t)(b * NCH + ch) * Dd + t * 4) = acc;
}

// Pass 4b: reduce partials -> aggregated. grid(B), 512 thr.
__global__ __launch_bounds__(512) void k_agg(const float* __restrict__ part,
                                             float* __restrict__ agg) {
  const int b = blockIdx.x, t = threadIdx.x;
  float acc = 0.f;
  for (int ch = 0; ch < NCH; ++ch) acc += part[(size_t)(b * NCH + ch) * Dd + t];
  agg[(size_t)b * Dd + t] = acc;
}

}  // namespace

extern "C" void kernel_launch(void* const* d_in, const int* in_sizes, int n_in,
                              void* d_out, int out_size, void* d_ws, size_t ws_size,
                              hipStream_t stream) {
  const float* x  = (const float*)d_in[0];
  const float* Wq = (const float*)d_in[1];
  const float* bq = (const float*)d_in[2];
  const float* Wk = (const float*)d_in[3];
  const float* bk = (const float*)d_in[4];

  float* out = (float*)d_out;
  float* agg = out;                       // [B][D]  (first tuple element)
  float* w   = out + (size_t)Bsz * Dd;    // [B][N]  (second tuple element)

  // workspace layout (floats): part | u | c | s   (~4.4 MiB total)
  float* part = (float*)d_ws;                        // B*NCH*D = 1048576
  float* u    = part + (size_t)Bsz * NCH * Dd;       // B*D     = 32768
  float* c    = u + (size_t)Bsz * Dd;                // B       = 64
  float* s    = c + Bsz;                             // B*N     = 65536

  k_colsum <<<dim3(Bsz, NCH), 128, 0, stream>>>(x, part);
  k_prep   <<<Bsz, 512, 0, stream>>>(part, Wq, bq, Wk, bk, u, c);
  k_scores <<<dim3(Bsz, 16), 256, 0, stream>>>(x, u, c, s);
  k_softmax<<<Bsz, 256, 0, stream>>>(s, w);
  k_wsum   <<<dim3(Bsz, NCH), 128, 0, stream>>>(x, w, part);
  k_agg    <<<Bsz, 512, 0, stream>>>(part, agg);
}

// Round 2
// 97.222 us; speedup vs baseline: 1.2176x; 1.2176x over previous
//
#include <hip/hip_runtime.h>
#include <math.h>

namespace {

constexpr int Bsz = 64;
constexpr int Nn  = 1024;
constexpr int Dd  = 512;
constexpr int NCH = 32;            // n-chunks for column-sum pass
constexpr int RPC = Nn / NCH;      // 32 rows per chunk
constexpr int SCH = 16;            // n-chunks for fused pass
constexpr int SRW = Nn / SCH;      // 64 rows per fused block
constexpr float SCALE = 0.044194173824159216f;  // 1/sqrt(512)

// Pass 1: partial column sums of x. grid(B, NCH), block 128.
__global__ __launch_bounds__(128) void k_colsum(const float* __restrict__ x,
                                                float* __restrict__ part) {
  const int b = blockIdx.x, ch = blockIdx.y, t = threadIdx.x;
  const float* base = x + ((size_t)b * Nn + (size_t)ch * RPC) * Dd;
  float4 acc = make_float4(0.f, 0.f, 0.f, 0.f);
  for (int n = 0; n < RPC; ++n) {
    float4 v = *reinterpret_cast<const float4*>(base + (size_t)n * Dd + t * 4);
    acc.x += v.x; acc.y += v.y; acc.z += v.z; acc.w += v.w;
  }
  *reinterpret_cast<float4*>(part + (size_t)(b * NCH + ch) * Dd + t * 4) = acc;
}

// Pass 2: xbar -> kbar = xbar@Wk^T + bk -> u = kbar@Wq, c = bq.kbar. grid(B), 512 thr.
__global__ __launch_bounds__(512) void k_prep(const float* __restrict__ part,
                                              const float* __restrict__ Wq,
                                              const float* __restrict__ bq,
                                              const float* __restrict__ Wk,
                                              const float* __restrict__ bk,
                                              float* __restrict__ u,
                                              float* __restrict__ c) {
  const int b = blockIdx.x, t = threadIdx.x;
  __shared__ __align__(16) float xbar[Dd];
  __shared__ float kbar[Dd];
  __shared__ float red[512];

  float acc = 0.f;
  for (int ch = 0; ch < NCH; ++ch) acc += part[(size_t)(b * NCH + ch) * Dd + t];
  xbar[t] = acc * (1.0f / Nn);
  __syncthreads();

  const float4* w4  = reinterpret_cast<const float4*>(Wk + (size_t)t * Dd);
  const float4* xb4 = reinterpret_cast<const float4*>(xbar);
  float s = 0.f;
  for (int i = 0; i < Dd / 4; ++i) {
    float4 wv = w4[i]; float4 xv = xb4[i];
    s += wv.x * xv.x + wv.y * xv.y + wv.z * xv.z + wv.w * xv.w;
  }
  kbar[t] = bk[t] + s;
  __syncthreads();

  float uu = 0.f;
  for (int e = 0; e < Dd; ++e) uu += kbar[e] * Wq[(size_t)e * Dd + t];
  u[(size_t)b * Dd + t] = uu;

  red[t] = bq[t] * kbar[t];
  __syncthreads();
  for (int off = 256; off > 0; off >>= 1) {
    if (t < off) red[t] += red[t + off];
    __syncthreads();
  }
  if (t == 0) c[b] = red[0];
}

// Pass 3 (fused): per row compute s[b,n], AND online-softmax-accumulate
// exp(s_n - m_chunk)*x_n into a per-block partial P[b,ch,:]. One x read total.
// grid(B, SCH), block 256 (4 waves, 16 rows each).
__global__ __launch_bounds__(256) void k_fused(const float* __restrict__ x,
                                               const float* __restrict__ u,
                                               const float* __restrict__ c,
                                               float* __restrict__ s,
                                               float* __restrict__ P,
                                               float* __restrict__ mch) {
  const int b = blockIdx.x, ch = blockIdx.y, t = threadIdx.x;
  const int wave = t >> 6, lane = t & 63;
  __shared__ __align__(16) float us[Dd];
  us[t]       = u[(size_t)b * Dd + t];
  us[t + 256] = u[(size_t)b * Dd + t + 256];
  __syncthreads();
  const float4 u1 = *reinterpret_cast<const float4*>(us + lane * 4);
  const float4 u2 = *reinterpret_cast<const float4*>(us + 256 + lane * 4);
  const float cb = c[b];

  float m = -3.0e38f;
  float4 a1 = make_float4(0.f, 0.f, 0.f, 0.f);
  float4 a2 = make_float4(0.f, 0.f, 0.f, 0.f);

  for (int r = wave; r < SRW; r += 4) {
    const int n = ch * SRW + r;
    const float4* xr = reinterpret_cast<const float4*>(x + ((size_t)b * Nn + n) * Dd);
    const float4 va = xr[lane];
    const float4 vb = xr[64 + lane];
    float dot = va.x * u1.x + va.y * u1.y + va.z * u1.z + va.w * u1.w
              + vb.x * u2.x + vb.y * u2.y + vb.z * u2.z + vb.w * u2.w;
    for (int off = 32; off > 0; off >>= 1) dot += __shfl_xor(dot, off);
    const float sn = (dot + cb) * SCALE;
    if (lane == 0) s[(size_t)b * Nn + n] = sn;
    if (sn > m) {                      // wave-uniform branch
      const float sc = __expf(m - sn); // first iter: exp(-inf) = 0
      a1.x *= sc; a1.y *= sc; a1.z *= sc; a1.w *= sc;
      a2.x *= sc; a2.y *= sc; a2.z *= sc; a2.w *= sc;
      m = sn;
    }
    const float e = __expf(sn - m);
    a1.x += e * va.x; a1.y += e * va.y; a1.z += e * va.z; a1.w += e * va.w;
    a2.x += e * vb.x; a2.y += e * vb.y; a2.z += e * vb.z; a2.w += e * vb.w;
  }

  // combine the 4 waves' accumulators under the block max
  __shared__ float wm[4];
  __shared__ __align__(16) float pacc[Dd];
  if (lane == 0) wm[wave] = m;
  pacc[t] = 0.f; pacc[t + 256] = 0.f;
  __syncthreads();
  const float mb = fmaxf(fmaxf(wm[0], wm[1]), fmaxf(wm[2], wm[3]));
  const float sw = __expf(m - mb);
  for (int wv = 0; wv < 4; ++wv) {
    if (wave == wv) {
      float4* p1 = reinterpret_cast<float4*>(pacc + lane * 4);
      float4* p2 = reinterpret_cast<float4*>(pacc + 256 + lane * 4);
      float4 t1 = *p1, t2 = *p2;
      t1.x += sw * a1.x; t1.y += sw * a1.y; t1.z += sw * a1.z; t1.w += sw * a1.w;
      t2.x += sw * a2.x; t2.y += sw * a2.y; t2.z += sw * a2.z; t2.w += sw * a2.w;
      *p1 = t1; *p2 = t2;
    }
    __syncthreads();
  }
  float* Pb = P + (size_t)(b * SCH + ch) * Dd;
  Pb[t]       = pacc[t];
  Pb[t + 256] = pacc[t + 256];
  if (t == 0) mch[b * SCH + ch] = mb;
}

// Pass 4: exact softmax over s -> w; combine chunk partials -> agg. grid(B), 256 thr.
__global__ __launch_bounds__(256) void k_final(const float* __restrict__ s,
                                               const float* __restrict__ P,
                                               const float* __restrict__ mch,
                                               float* __restrict__ w,
                                               float* __restrict__ agg) {
  const int b = blockIdx.x, t = threadIdx.x;
  const int wave = t >> 6, lane = t & 63;
  __shared__ float lred[4];
  __shared__ float coef[SCH];

  float v[4];
  for (int i = 0; i < 4; ++i) v[i] = s[(size_t)b * Nn + t + i * 256];
  float m = fmaxf(fmaxf(v[0], v[1]), fmaxf(v[2], v[3]));
  for (int off = 32; off > 0; off >>= 1) m = fmaxf(m, __shfl_xor(m, off));
  if (lane == 0) lred[wave] = m;
  __syncthreads();
  m = fmaxf(fmaxf(lred[0], lred[1]), fmaxf(lred[2], lred[3]));
  __syncthreads();

  float e[4];
  float sum = 0.f;
  for (int i = 0; i < 4; ++i) { e[i] = expf(v[i] - m); sum += e[i]; }
  for (int off = 32; off > 0; off >>= 1) sum += __shfl_xor(sum, off);
  if (lane == 0) lred[wave] = sum;
  __syncthreads();
  sum = lred[0] + lred[1] + lred[2] + lred[3];
  const float inv = 1.0f / sum;
  for (int i = 0; i < 4; ++i) w[(size_t)b * Nn + t + i * 256] = e[i] * inv;

  if (t < SCH) coef[t] = expf(mch[b * SCH + t] - m) * inv;
  __syncthreads();

  for (int d = t; d < Dd; d += 256) {
    float acc = 0.f;
    for (int chh = 0; chh < SCH; ++chh)
      acc += P[(size_t)(b * SCH + chh) * Dd + d] * coef[chh];
    agg[(size_t)b * Dd + d] = acc;
  }
}

}  // namespace

extern "C" void kernel_launch(void* const* d_in, const int* in_sizes, int n_in,
                              void* d_out, int out_size, void* d_ws, size_t ws_size,
                              hipStream_t stream) {
  const float* x  = (const float*)d_in[0];
  const float* Wq = (const float*)d_in[1];
  const float* bq = (const float*)d_in[2];
  const float* Wk = (const float*)d_in[3];
  const float* bk = (const float*)d_in[4];

  float* out = (float*)d_out;
  float* agg = out;                       // [B][D]
  float* w   = out + (size_t)Bsz * Dd;    // [B][N]

  // workspace (floats): part | u | c | s | P | mch   (~6.7 MiB)
  float* part = (float*)d_ws;                         // B*NCH*D
  float* u    = part + (size_t)Bsz * NCH * Dd;        // B*D
  float* c    = u + (size_t)Bsz * Dd;                 // B
  float* s    = c + Bsz;                              // B*N
  float* P    = s + (size_t)Bsz * Nn;                 // B*SCH*D
  float* mch  = P + (size_t)Bsz * SCH * Dd;           // B*SCH

  k_colsum<<<dim3(Bsz, NCH), 128, 0, stream>>>(x, part);
  k_prep  <<<Bsz, 512, 0, stream>>>(part, Wq, bq, Wk, bk, u, c);
  k_fused <<<dim3(Bsz, SCH), 256, 0, stream>>>(x, u, c, s, P, mch);
  k_final <<<Bsz, 256, 0, stream>>>(s, P, mch, w, agg);
}